// Round 1
// baseline (1004.972 us; speedup 1.0000x reference)
//
#include <hip/hip_runtime.h>
#include <math.h>

#define BB 8
#define SS 512
#define DD 768
#define HH 12
#define DKK 64
#define NTOK (BB*SS)                       // 4096
#define NELEM (25165824ull)                // B*H*S*S
#define TQ 8
#define KC 64
#define SCALEQ 0.03608439182435161f        // 1/sqrt(768)

__global__ __launch_bounds__(64)
void init_loss_kernel(float* lossp) {
    if (threadIdx.x == 0) *lossp = 0.0f;
}

// ---------------------------------------------------------------------------
// Fused projection GEMM: C_z[4096][768] = X_z @ W_z + b_z  (scaled for q-side)
// z = 0..5 : (query,Wql)(key,Wkl)(query,Wqr)(key,Wkr)(query,Wq)(key,Wk)
// Tiling: BM=BN=64, BK=16, 256 threads, 4x4 per-thread microtile.
// ---------------------------------------------------------------------------
__global__ __launch_bounds__(256)
void proj_gemm(const float* __restrict__ query, const float* __restrict__ key,
               const float* __restrict__ W0, const float* __restrict__ b0,
               const float* __restrict__ W1, const float* __restrict__ b1,
               const float* __restrict__ W2, const float* __restrict__ b2,
               const float* __restrict__ W3, const float* __restrict__ b3,
               const float* __restrict__ W4, const float* __restrict__ b4,
               const float* __restrict__ W5, const float* __restrict__ b5,
               float* __restrict__ outbuf)
{
    __shared__ float As[16][68];   // k-major A tile (transposed on store)
    __shared__ float Bs[16][68];

    const int z = blockIdx.z;
    const float* X = (z & 1) ? key : query;
    const float* W; const float* bias;
    switch (z) {
        case 0: W = W0; bias = b0; break;
        case 1: W = W1; bias = b1; break;
        case 2: W = W2; bias = b2; break;
        case 3: W = W3; bias = b3; break;
        case 4: W = W4; bias = b4; break;
        default: W = W5; bias = b5; break;
    }
    const float scl = (z & 1) ? 1.0f : SCALEQ;
    float* C = outbuf + (size_t)z * NTOK * DD;

    const int t  = threadIdx.x;
    const int tx = t & 15, ty = t >> 4;
    const int m0 = blockIdx.y * 64, n0 = blockIdx.x * 64;

    const int lam = t >> 2;            // A row within tile (0..63)
    const int lak = (t & 3) << 2;      // A k-offset {0,4,8,12}
    const int lbk = t >> 4;            // B k within tile (0..15)
    const int lbn = (t & 15) << 2;     // B n-offset

    float acc[4][4];
#pragma unroll
    for (int i = 0; i < 4; ++i)
#pragma unroll
        for (int jj = 0; jj < 4; ++jj) acc[i][jj] = 0.0f;

    for (int k0 = 0; k0 < DD; k0 += 16) {
        float4 av = *(const float4*)(X + (size_t)(m0 + lam) * DD + k0 + lak);
        As[lak + 0][lam] = av.x;
        As[lak + 1][lam] = av.y;
        As[lak + 2][lam] = av.z;
        As[lak + 3][lam] = av.w;
        *(float4*)&Bs[lbk][lbn] =
            *(const float4*)(W + (size_t)(k0 + lbk) * DD + n0 + lbn);
        __syncthreads();
#pragma unroll
        for (int kk = 0; kk < 16; ++kk) {
            float4 a  = *(const float4*)&As[kk][ty * 4];
            float4 bv = *(const float4*)&Bs[kk][tx * 4];
            float a_[4] = {a.x, a.y, a.z, a.w};
            float b_[4] = {bv.x, bv.y, bv.z, bv.w};
#pragma unroll
            for (int i = 0; i < 4; ++i)
#pragma unroll
                for (int jj = 0; jj < 4; ++jj) acc[i][jj] += a_[i] * b_[jj];
        }
        __syncthreads();
    }

    float4 bb = *(const float4*)(bias + n0 + tx * 4);
    float bias4[4] = {bb.x, bb.y, bb.z, bb.w};
#pragma unroll
    for (int i = 0; i < 4; ++i) {
        float4 o;
        o.x = (acc[i][0] + bias4[0]) * scl;
        o.y = (acc[i][1] + bias4[1]) * scl;
        o.z = (acc[i][2] + bias4[2]) * scl;
        o.w = (acc[i][3] + bias4[3]) * scl;
        *(float4*)(C + (size_t)(m0 + ty * 4 + i) * DD + n0 + tx * 4) = o;
    }
}

// ---------------------------------------------------------------------------
// Attention kernel: one block per (b, h, q-tile of 8 rows).
// Stage L: theta_l softmax (k<=q) -> forward cumsum -> smb
// Stage R: theta_r softmax (k>=q) -> reverse cumsum -> smb *= ...
// Stage M: (scores - rmq - rmk) * smb -> softmax -> p, BCE loss.
// ---------------------------------------------------------------------------
__global__ __launch_bounds__(256)
void attn_kernel(const float* __restrict__ QL, const float* __restrict__ KLp,
                 const float* __restrict__ QR, const float* __restrict__ KRp,
                 const float* __restrict__ QM, const float* __restrict__ KMp,
                 const float* __restrict__ mask, const float* __restrict__ span,
                 float* __restrict__ outp, float* __restrict__ lossp)
{
    __shared__ float smb[TQ][SS];      // 16 KB  soft mask accumulation
    __shared__ float curb[TQ][SS];     // 16 KB  current scores
    __shared__ float Kt[KC][DKK + 4];  // 17 KB  K chunk (pad 68 for banking)
    __shared__ float Qs[TQ][DKK];      //  2 KB
    __shared__ float lred[4];

    const int t  = threadIdx.x;
    const int blk = blockIdx.x;
    const int qt = blk & 63;           // 64 q-tiles of 8 rows
    const int bh = blk >> 6;
    const int b  = bh / HH;
    const int h  = bh % HH;

    const int c64 = t & 63, rw = t >> 6;   // score-compute mapping
    const int r = t >> 5, j = t & 31;      // row-op mapping (32 lanes/row)
    const int qrow = qt * TQ + r;

    auto compute_scores = [&](const float* Qg, const float* Kg) {
        if (t < 128) {
            int rr = t >> 4, d0 = (t & 15) << 2;
            *(float4*)&Qs[rr][d0] =
                *(const float4*)(Qg + ((size_t)(b * SS + qt * TQ + rr)) * DD + h * DKK + d0);
        }
        __syncthreads();   // Qs ready; also fences prior row-op reads of curb
        for (int kc = 0; kc < SS / KC; ++kc) {
            {
                int kk = t >> 2, d0 = (t & 3) << 4;
                const float* src = Kg + ((size_t)(b * SS + kc * KC + kk)) * DD + h * DKK + d0;
                float4 v0 = *(const float4*)(src);
                float4 v1 = *(const float4*)(src + 4);
                float4 v2 = *(const float4*)(src + 8);
                float4 v3 = *(const float4*)(src + 12);
                *(float4*)&Kt[kk][d0]      = v0;
                *(float4*)&Kt[kk][d0 + 4]  = v1;
                *(float4*)&Kt[kk][d0 + 8]  = v2;
                *(float4*)&Kt[kk][d0 + 12] = v3;
            }
            __syncthreads();
            float a0 = 0.0f, a1 = 0.0f;
#pragma unroll
            for (int d = 0; d < DKK; d += 4) {
                float4 kv = *(const float4*)&Kt[c64][d];
                float4 q0 = *(const float4*)&Qs[rw][d];
                float4 q1 = *(const float4*)&Qs[rw + 4][d];
                a0 += kv.x * q0.x + kv.y * q0.y + kv.z * q0.z + kv.w * q0.w;
                a1 += kv.x * q1.x + kv.y * q1.y + kv.z * q1.z + kv.w * q1.w;
            }
            curb[rw][kc * KC + c64]     = a0;
            curb[rw + 4][kc * KC + c64] = a1;
            __syncthreads();
        }
    };

    // ---------------- Stage L ----------------
    compute_scores(QL, KLp);
    {
        float e[16];
        float mx = -3.0e38f;
#pragma unroll
        for (int u = 0; u < 16; ++u) {
            int c = u * 32 + j;
            float v = curb[r][c];
            if (c <= qrow && v > mx) mx = v;
        }
#pragma unroll
        for (int off = 16; off >= 1; off >>= 1) mx = fmaxf(mx, __shfl_xor(mx, off));
        float sum = 0.0f;
#pragma unroll
        for (int u = 0; u < 16; ++u) {
            int c = u * 32 + j;
            float v = (c <= qrow) ? __expf(curb[r][c] - mx) : 0.0f;
            e[u] = v; sum += v;
        }
#pragma unroll
        for (int off = 16; off >= 1; off >>= 1) sum += __shfl_xor(sum, off);
        float inv = 1.0f / sum;
        float run = 0.0f;
#pragma unroll
        for (int u = 0; u < 16; ++u) {
            float sc = e[u];
#pragma unroll
            for (int off = 1; off < 32; off <<= 1) {
                float w = __shfl_up(sc, off, 32);
                if (j >= off) sc += w;
            }
            smb[r][u * 32 + j] = (run + sc) * inv;
            run += __shfl(sc, 31, 32);
        }
    }

    // ---------------- Stage R ----------------
    compute_scores(QR, KRp);
    {
        float e[16];
        float mx = -3.0e38f;
#pragma unroll
        for (int u = 0; u < 16; ++u) {
            int c = u * 32 + j;
            float v = curb[r][c];
            if (c >= qrow && v > mx) mx = v;
        }
#pragma unroll
        for (int off = 16; off >= 1; off >>= 1) mx = fmaxf(mx, __shfl_xor(mx, off));
        float sum = 0.0f;
#pragma unroll
        for (int u = 0; u < 16; ++u) {
            int c = u * 32 + j;
            float v = (c >= qrow) ? __expf(curb[r][c] - mx) : 0.0f;
            e[u] = v; sum += v;
        }
#pragma unroll
        for (int off = 16; off >= 1; off >>= 1) sum += __shfl_xor(sum, off);
        float inv = 1.0f / sum;
        float run = 0.0f;
#pragma unroll
        for (int u = 15; u >= 0; --u) {
            float sc = e[u];
#pragma unroll
            for (int off = 1; off < 32; off <<= 1) {
                float w = __shfl_down(sc, off, 32);
                if (j + off < 32) sc += w;
            }
            smb[r][u * 32 + j] *= (run + sc) * inv;
            run += __shfl(sc, 0, 32);
        }
    }

    // ---------------- Stage M ----------------
    compute_scores(QM, KMp);
    {
        float mv  = mask[b * SS + qrow];
        float rmq = (mv == -10000.0f) ? 1.0e9f : mv;
        float vb[16];
        float mx = -3.0e38f;
#pragma unroll
        for (int u = 0; u < 16; ++u) {
            int c = u * 32 + j;
            float mk  = mask[b * SS + c];
            float rmk = (mk == -10000.0f) ? 1.0e9f : mk;
            float v = (curb[r][c] - rmq - rmk) * smb[r][c];
            vb[u] = v;
            mx = fmaxf(mx, v);
        }
#pragma unroll
        for (int off = 16; off >= 1; off >>= 1) mx = fmaxf(mx, __shfl_xor(mx, off));
        float sum = 0.0f;
#pragma unroll
        for (int u = 0; u < 16; ++u) {
            float ev = __expf(vb[u] - mx);
            vb[u] = ev; sum += ev;
        }
#pragma unroll
        for (int off = 16; off >= 1; off >>= 1) sum += __shfl_xor(sum, off);
        float inv = 1.0f / sum;

        float* orow = outp + (((size_t)(b * HH + h) * SS + qrow)) * SS;
        const float* sprow = span + (((size_t)(h * BB + b) * SS + qrow)) * SS;
        float lsum = 0.0f;
#pragma unroll
        for (int u = 0; u < 16; ++u) {
            int c = u * 32 + j;
            float p = vb[u] * inv;
            orow[c] = p;
            float s = sprow[c];
            lsum += log1pf(__expf(-p)) + (1.0f - s) * p;
        }
#pragma unroll
        for (int off = 32; off >= 1; off >>= 1) lsum += __shfl_xor(lsum, off);
        if ((t & 63) == 0) lred[t >> 6] = lsum;
        __syncthreads();
        if (t == 0)
            atomicAdd(lossp, (lred[0] + lred[1] + lred[2] + lred[3]) *
                                 (float)(1.0 / 25165824.0));
    }
}

extern "C" void kernel_launch(void* const* d_in, const int* in_sizes, int n_in,
                              void* d_out, int out_size, void* d_ws, size_t ws_size,
                              hipStream_t stream)
{
    const float* query = (const float*)d_in[0];
    const float* key_t = (const float*)d_in[1];
    const float* mask  = (const float*)d_in[2];
    const float* span  = (const float*)d_in[3];
    const float* Wql = (const float*)d_in[4];  const float* bql = (const float*)d_in[5];
    const float* Wkl = (const float*)d_in[6];  const float* bkl = (const float*)d_in[7];
    const float* Wqr = (const float*)d_in[8];  const float* bqr = (const float*)d_in[9];
    const float* Wkr = (const float*)d_in[10]; const float* bkr = (const float*)d_in[11];
    const float* Wq  = (const float*)d_in[12]; const float* bq  = (const float*)d_in[13];
    const float* Wk  = (const float*)d_in[14]; const float* bk  = (const float*)d_in[15];

    float* out = (float*)d_out;
    float* ws  = (float*)d_ws;

    const size_t NPROJ = (size_t)NTOK * DD;   // 3,145,728 floats per projection
    float* projs = ws;                        // 6 buffers: QL KL QR KR QM KM

    float* lossp = out + NELEM;

    init_loss_kernel<<<dim3(1), dim3(64), 0, stream>>>(lossp);

    proj_gemm<<<dim3(DD / 64, NTOK / 64, 6), dim3(256), 0, stream>>>(
        query, key_t,
        Wql, bql, Wkl, bkl, Wqr, bqr, Wkr, bkr, Wq, bq, Wk, bk,
        projs);

    const float* QL = projs + 0 * NPROJ;
    const float* KL = projs + 1 * NPROJ;
    const float* QR = projs + 2 * NPROJ;
    const float* KR = projs + 3 * NPROJ;
    const float* QM = projs + 4 * NPROJ;
    const float* KM = projs + 5 * NPROJ;

    attn_kernel<<<dim3(96 * 64), dim3(256), 0, stream>>>(
        QL, KL, QR, KR, QM, KM, mask, span, out, lossp);
}

// Round 2
// 646.684 us; speedup vs baseline: 1.5540x; 1.5540x over previous
//
#include <hip/hip_runtime.h>
#include <math.h>

#define BB 8
#define SS 512
#define DD 768
#define HH 12
#define DKK 64
#define NTOK (BB*SS)                       // 4096
#define NELEM (25165824ull)                // B*H*S*S
#define NPROJ 3145728                      // 4096*768 elements per projection
#define WSZ   589824                       // 768*768
#define SCALEQ 0.03608439182435161f        // 1/sqrt(768)

typedef unsigned short u16;
typedef short short8 __attribute__((ext_vector_type(8)));
typedef float f32x4 __attribute__((ext_vector_type(4)));
typedef unsigned short u16x4 __attribute__((ext_vector_type(4)));

#define MFMA16 __builtin_amdgcn_mfma_f32_16x16x32_bf16

__device__ inline u16 f32_to_bf16(float f) {
    unsigned int u = __float_as_uint(f);
    unsigned int r = u + 0x7fffu + ((u >> 16) & 1u);   // RNE
    return (u16)(r >> 16);
}
__device__ inline float bf16_to_f32(u16 h) {
    return __uint_as_float(((unsigned int)h) << 16);
}

__global__ __launch_bounds__(64)
void init_loss_kernel(float* lossp) {
    if (threadIdx.x == 0) *lossp = 0.0f;
}

// ---------------------------------------------------------------------------
// Transpose + split-cast the 6 weight matrices: W[768][768] f32 ->
// WT_hi/WT_lo[768][768] bf16 with WT[n][k] = W[k][n].
// ---------------------------------------------------------------------------
__global__ __launch_bounds__(256)
void cast_wT(const float* __restrict__ W0, const float* __restrict__ W1,
             const float* __restrict__ W2, const float* __restrict__ W3,
             const float* __restrict__ W4, const float* __restrict__ W5,
             u16* __restrict__ WTh, u16* __restrict__ WTl)
{
    __shared__ float tile[32][33];
    const int z = blockIdx.z;
    const float* W;
    switch (z) {
        case 0: W = W0; break; case 1: W = W1; break; case 2: W = W2; break;
        case 3: W = W3; break; case 4: W = W4; break; default: W = W5; break;
    }
    u16* th = WTh + (size_t)z * WSZ;
    u16* tl = WTl + (size_t)z * WSZ;
    const int t = threadIdx.x;
    const int k0 = blockIdx.y * 32, n0 = blockIdx.x * 32;
    const int rr = t >> 3, c0 = (t & 7) * 4;

    float4 v = *(const float4*)(W + (size_t)(k0 + rr) * DD + n0 + c0);
    tile[rr][c0 + 0] = v.x; tile[rr][c0 + 1] = v.y;
    tile[rr][c0 + 2] = v.z; tile[rr][c0 + 3] = v.w;
    __syncthreads();

    u16x4 hw, lw;
#pragma unroll
    for (int i = 0; i < 4; ++i) {
        float f = tile[c0 + i][rr];
        u16 hi = f32_to_bf16(f);
        hw[i] = hi;
        lw[i] = f32_to_bf16(f - bf16_to_f32(hi));
    }
    size_t o = (size_t)(n0 + rr) * DD + k0 + c0;
    *(u16x4*)&th[o] = hw;
    *(u16x4*)&tl[o] = lw;
}

// ---------------------------------------------------------------------------
// Projection GEMM (bf16x3 MFMA): C_z = X_z @ W_z + b_z, scaled on q-side.
// 128x128 tile, BK=32, 256 threads (4 waves, each 64x64).
// Emits proj hi bf16 (all z) and lo bf16 (z<4 only).
// ---------------------------------------------------------------------------
__global__ __launch_bounds__(256)
void proj_gemm_mfma(const float* __restrict__ query, const float* __restrict__ key,
                    const u16* __restrict__ WTh, const u16* __restrict__ WTl,
                    const float* __restrict__ b0, const float* __restrict__ b1,
                    const float* __restrict__ b2, const float* __restrict__ b3,
                    const float* __restrict__ b4, const float* __restrict__ b5,
                    u16* __restrict__ Ph, u16* __restrict__ Pl)
{
    __shared__ alignas(16) u16 Ash[128][40];   // pad 40: 80B rows, 16B-aligned, 2-way banks
    __shared__ alignas(16) u16 Asl[128][40];
    __shared__ alignas(16) u16 Bsh[128][40];
    __shared__ alignas(16) u16 Bsl[128][40];

    const int z = blockIdx.z;
    const float* X = (z & 1) ? key : query;
    const float* bias;
    switch (z) {
        case 0: bias = b0; break; case 1: bias = b1; break; case 2: bias = b2; break;
        case 3: bias = b3; break; case 4: bias = b4; break; default: bias = b5; break;
    }
    const float scl = (z & 1) ? 1.0f : SCALEQ;
    const u16* WThz = WTh + (size_t)z * WSZ;
    const u16* WTlz = WTl + (size_t)z * WSZ;
    u16* Ch = Ph + (size_t)z * NPROJ;
    u16* Cl = Pl + (size_t)z * NPROJ;
    const bool wlo = (z < 4);

    const int t = threadIdx.x;
    const int w = t >> 6, l = t & 63, quad = l >> 4, ln = l & 15;
    const int m0 = blockIdx.y * 128, n0 = blockIdx.x * 128;
    const int wm = (w & 1) * 64, wn = (w >> 1) * 64;

    const int arow = t >> 1, akoff = (t & 1) * 16;   // A: 16 f32/thread
    const int brow = t >> 1, bkoff = (t & 1) * 16;   // B: 16 bf16/thread per buf

    f32x4 acc[4][4];
#pragma unroll
    for (int i = 0; i < 4; ++i)
#pragma unroll
        for (int jj = 0; jj < 4; ++jj) acc[i][jj] = (f32x4){0.f, 0.f, 0.f, 0.f};

    for (int k0 = 0; k0 < DD; k0 += 32) {
        // --- stage A (f32 -> hi/lo bf16) ---
        {
            const float* asrc = X + (size_t)(m0 + arow) * DD + k0 + akoff;
            float fa[16];
            *(float4*)&fa[0]  = *(const float4*)(asrc + 0);
            *(float4*)&fa[4]  = *(const float4*)(asrc + 4);
            *(float4*)&fa[8]  = *(const float4*)(asrc + 8);
            *(float4*)&fa[12] = *(const float4*)(asrc + 12);
            short8 h0, h1, l0, l1;
#pragma unroll
            for (int i = 0; i < 8; ++i) {
                u16 hi = f32_to_bf16(fa[i]);
                h0[i] = (short)hi;
                l0[i] = (short)f32_to_bf16(fa[i] - bf16_to_f32(hi));
                u16 hi2 = f32_to_bf16(fa[8 + i]);
                h1[i] = (short)hi2;
                l1[i] = (short)f32_to_bf16(fa[8 + i] - bf16_to_f32(hi2));
            }
            *(short8*)&Ash[arow][akoff]     = h0;
            *(short8*)&Ash[arow][akoff + 8] = h1;
            *(short8*)&Asl[arow][akoff]     = l0;
            *(short8*)&Asl[arow][akoff + 8] = l1;
        }
        // --- stage B (pre-cast bf16 hi/lo) ---
        {
            const u16* bh = WThz + (size_t)(n0 + brow) * DD + k0 + bkoff;
            const u16* bl = WTlz + (size_t)(n0 + brow) * DD + k0 + bkoff;
            *(uint4*)&Bsh[brow][bkoff]     = *(const uint4*)(bh);
            *(uint4*)&Bsh[brow][bkoff + 8] = *(const uint4*)(bh + 8);
            *(uint4*)&Bsl[brow][bkoff]     = *(const uint4*)(bl);
            *(uint4*)&Bsl[brow][bkoff + 8] = *(const uint4*)(bl + 8);
        }
        __syncthreads();

        short8 afh[4], afl[4], bfh[4], bfl[4];
#pragma unroll
        for (int mt = 0; mt < 4; ++mt) {
            afh[mt] = *(const short8*)&Ash[wm + mt * 16 + ln][quad * 8];
            afl[mt] = *(const short8*)&Asl[wm + mt * 16 + ln][quad * 8];
        }
#pragma unroll
        for (int nt = 0; nt < 4; ++nt) {
            bfh[nt] = *(const short8*)&Bsh[wn + nt * 16 + ln][quad * 8];
            bfl[nt] = *(const short8*)&Bsl[wn + nt * 16 + ln][quad * 8];
        }
#pragma unroll
        for (int mt = 0; mt < 4; ++mt)
#pragma unroll
            for (int nt = 0; nt < 4; ++nt) {
                acc[mt][nt] = MFMA16(afh[mt], bfh[nt], acc[mt][nt], 0, 0, 0);
                acc[mt][nt] = MFMA16(afh[mt], bfl[nt], acc[mt][nt], 0, 0, 0);
                acc[mt][nt] = MFMA16(afl[mt], bfh[nt], acc[mt][nt], 0, 0, 0);
            }
        __syncthreads();
    }

    // --- epilogue: bias + scale, split to hi/lo bf16 ---
#pragma unroll
    for (int nt = 0; nt < 4; ++nt) {
        const int n = n0 + wn + nt * 16 + ln;
        const float bv = bias[n];
#pragma unroll
        for (int mt = 0; mt < 4; ++mt) {
            const int mbase = m0 + wm + mt * 16 + quad * 4;
#pragma unroll
            for (int reg = 0; reg < 4; ++reg) {
                float c = (acc[mt][nt][reg] + bv) * scl;
                u16 hi = f32_to_bf16(c);
                size_t o = (size_t)(mbase + reg) * DD + n;
                Ch[o] = hi;
                if (wlo) Cl[o] = f32_to_bf16(c - bf16_to_f32(hi));
            }
        }
    }
}

// ---------------------------------------------------------------------------
// Attention: one block per (b,h, 16-row q-tile). 512 threads (8 waves).
// Scores via 16x16x32 bf16 MFMA (3-term hi/lo for L/R, hi-only for M).
// ---------------------------------------------------------------------------
#define CHK 128
__global__ __launch_bounds__(512)
void attn_mfma(const u16* __restrict__ Ph, const u16* __restrict__ Pl,
               const float* __restrict__ mask, const float* __restrict__ span,
               float* __restrict__ outp, float* __restrict__ lossp)
{
    __shared__ alignas(16) u16 Kth[CHK][72];   // 144B rows: 16B-aligned, 2-way banks
    __shared__ alignas(16) u16 Ktl[CHK][72];
    __shared__ alignas(16) u16 Qsh[16][72];
    __shared__ alignas(16) u16 Qsl[16][72];
    __shared__ float curb[16][516];
    __shared__ float smb[16][516];
    __shared__ float lred[8];

    const int t = threadIdx.x;
    const int blk = blockIdx.x;
    const int qt = blk & 31;
    const int bh = blk >> 5;
    const int b = bh / HH, h = bh % HH;
    const int w = t >> 6, l = t & 63, quad = l >> 4, ln = l & 15;
    const int r = t >> 5, j = t & 31;          // row-op mapping: 16 rows x 32 lanes
    const int qrow = qt * 16 + r;

    auto compute_scores = [&](const u16* Qh, const u16* Ql,
                              const u16* Kh, const u16* Kl, bool use_lo) {
        __syncthreads();                        // prior-stage readers done
        if (t < 256) {
            int which = t >> 7, tt = t & 127;
            int row = tt >> 3, co = (tt & 7) * 8;
            if (!which) {
                const u16* src = Qh + (size_t)(b * SS + qt * 16 + row) * DD + h * DKK + co;
                *(uint4*)&Qsh[row][co] = *(const uint4*)src;
            } else if (use_lo) {
                const u16* src = Ql + (size_t)(b * SS + qt * 16 + row) * DD + h * DKK + co;
                *(uint4*)&Qsl[row][co] = *(const uint4*)src;
            }
        }
        __syncthreads();
        short8 ah0 = *(const short8*)&Qsh[ln][quad * 8];
        short8 ah1 = *(const short8*)&Qsh[ln][32 + quad * 8];
        short8 al0 = ah0, al1 = ah1;
        if (use_lo) {
            al0 = *(const short8*)&Qsl[ln][quad * 8];
            al1 = *(const short8*)&Qsl[ln][32 + quad * 8];
        }
        for (int kc = 0; kc < SS / CHK; ++kc) {
            {
                int row = t >> 2, co = (t & 3) * 16;
                const u16* src = Kh + (size_t)(b * SS + kc * CHK + row) * DD + h * DKK + co;
                *(uint4*)&Kth[row][co]     = *(const uint4*)(src);
                *(uint4*)&Kth[row][co + 8] = *(const uint4*)(src + 8);
                if (use_lo) {
                    const u16* src2 = Kl + (size_t)(b * SS + kc * CHK + row) * DD + h * DKK + co;
                    *(uint4*)&Ktl[row][co]     = *(const uint4*)(src2);
                    *(uint4*)&Ktl[row][co + 8] = *(const uint4*)(src2 + 8);
                }
            }
            __syncthreads();
            const int nb = w * 16;
            short8 bh0 = *(const short8*)&Kth[nb + ln][quad * 8];
            short8 bh1 = *(const short8*)&Kth[nb + ln][32 + quad * 8];
            f32x4 acc = (f32x4){0.f, 0.f, 0.f, 0.f};
            acc = MFMA16(ah0, bh0, acc, 0, 0, 0);
            acc = MFMA16(ah1, bh1, acc, 0, 0, 0);
            if (use_lo) {
                short8 bl0 = *(const short8*)&Ktl[nb + ln][quad * 8];
                short8 bl1 = *(const short8*)&Ktl[nb + ln][32 + quad * 8];
                acc = MFMA16(ah0, bl0, acc, 0, 0, 0);
                acc = MFMA16(ah1, bl1, acc, 0, 0, 0);
                acc = MFMA16(al0, bh0, acc, 0, 0, 0);
                acc = MFMA16(al1, bh1, acc, 0, 0, 0);
            }
            const int cbase = kc * CHK + nb + ln;
#pragma unroll
            for (int reg = 0; reg < 4; ++reg)
                curb[quad * 4 + reg][cbase] = acc[reg];
            __syncthreads();
        }
    };

    // ---------------- Stage L ----------------
    compute_scores(Ph + 0 * (size_t)NPROJ, Pl + 0 * (size_t)NPROJ,
                   Ph + 1 * (size_t)NPROJ, Pl + 1 * (size_t)NPROJ, true);
    {
        float e[16];
        float mx = -3.0e38f;
#pragma unroll
        for (int u = 0; u < 16; ++u) {
            int c = u * 32 + j;
            float v = curb[r][c];
            if (c <= qrow && v > mx) mx = v;
        }
#pragma unroll
        for (int off = 16; off >= 1; off >>= 1) mx = fmaxf(mx, __shfl_xor(mx, off));
        float sum = 0.0f;
#pragma unroll
        for (int u = 0; u < 16; ++u) {
            int c = u * 32 + j;
            float v = (c <= qrow) ? __expf(curb[r][c] - mx) : 0.0f;
            e[u] = v; sum += v;
        }
#pragma unroll
        for (int off = 16; off >= 1; off >>= 1) sum += __shfl_xor(sum, off);
        float inv = 1.0f / sum;
        float run = 0.0f;
#pragma unroll
        for (int u = 0; u < 16; ++u) {
            float sc = e[u];
#pragma unroll
            for (int off = 1; off < 32; off <<= 1) {
                float ww = __shfl_up(sc, off, 32);
                if (j >= off) sc += ww;
            }
            smb[r][u * 32 + j] = (run + sc) * inv;
            run += __shfl(sc, 31, 32);
        }
    }

    // ---------------- Stage R ----------------
    compute_scores(Ph + 2 * (size_t)NPROJ, Pl + 2 * (size_t)NPROJ,
                   Ph + 3 * (size_t)NPROJ, Pl + 3 * (size_t)NPROJ, true);
    {
        float e[16];
        float mx = -3.0e38f;
#pragma unroll
        for (int u = 0; u < 16; ++u) {
            int c = u * 32 + j;
            float v = curb[r][c];
            if (c >= qrow && v > mx) mx = v;
        }
#pragma unroll
        for (int off = 16; off >= 1; off >>= 1) mx = fmaxf(mx, __shfl_xor(mx, off));
        float sum = 0.0f;
#pragma unroll
        for (int u = 0; u < 16; ++u) {
            int c = u * 32 + j;
            float v = (c >= qrow) ? __expf(curb[r][c] - mx) : 0.0f;
            e[u] = v; sum += v;
        }
#pragma unroll
        for (int off = 16; off >= 1; off >>= 1) sum += __shfl_xor(sum, off);
        float inv = 1.0f / sum;
        float run = 0.0f;
#pragma unroll
        for (int u = 15; u >= 0; --u) {
            float sc = e[u];
#pragma unroll
            for (int off = 1; off < 32; off <<= 1) {
                float ww = __shfl_down(sc, off, 32);
                if (j + off < 32) sc += ww;
            }
            smb[r][u * 32 + j] *= (run + sc) * inv;
            run += __shfl(sc, 0, 32);
        }
    }

    // ---------------- Stage M ----------------
    compute_scores(Ph + 4 * (size_t)NPROJ, (const u16*)0,
                   Ph + 5 * (size_t)NPROJ, (const u16*)0, false);
    {
        float mv  = mask[b * SS + qrow];
        float rmq = (mv == -10000.0f) ? 1.0e9f : mv;
        float vb[16];
        float mx = -3.0e38f;
#pragma unroll
        for (int u = 0; u < 16; ++u) {
            int c = u * 32 + j;
            float mk  = mask[b * SS + c];
            float rmk = (mk == -10000.0f) ? 1.0e9f : mk;
            float v = (curb[r][c] - rmq - rmk) * smb[r][c];
            vb[u] = v;
            mx = fmaxf(mx, v);
        }
#pragma unroll
        for (int off = 16; off >= 1; off >>= 1) mx = fmaxf(mx, __shfl_xor(mx, off));
        float sum = 0.0f;
#pragma unroll
        for (int u = 0; u < 16; ++u) {
            float ev = __expf(vb[u] - mx);
            vb[u] = ev; sum += ev;
        }
#pragma unroll
        for (int off = 16; off >= 1; off >>= 1) sum += __shfl_xor(sum, off);
        float inv = 1.0f / sum;

        float* orow = outp + (((size_t)(b * HH + h) * SS + qrow)) * SS;
        const float* sprow = span + (((size_t)(h * BB + b) * SS + qrow)) * SS;
        float lsum = 0.0f;
#pragma unroll
        for (int u = 0; u < 16; ++u) {
            int c = u * 32 + j;
            float p = vb[u] * inv;
            orow[c] = p;
            float s = sprow[c];
            lsum += log1pf(__expf(-p)) + (1.0f - s) * p;
        }
#pragma unroll
        for (int off = 32; off >= 1; off >>= 1) lsum += __shfl_xor(lsum, off);
        if ((t & 63) == 0) lred[t >> 6] = lsum;
        __syncthreads();
        if (t == 0) {
            float tot = 0.0f;
#pragma unroll
            for (int i = 0; i < 8; ++i) tot += lred[i];
            atomicAdd(lossp, tot * (float)(1.0 / 25165824.0));
        }
    }
}

extern "C" void kernel_launch(void* const* d_in, const int* in_sizes, int n_in,
                              void* d_out, int out_size, void* d_ws, size_t ws_size,
                              hipStream_t stream)
{
    const float* query = (const float*)d_in[0];
    const float* key_t = (const float*)d_in[1];
    const float* mask  = (const float*)d_in[2];
    const float* span  = (const float*)d_in[3];
    const float* Wql = (const float*)d_in[4];  const float* bql = (const float*)d_in[5];
    const float* Wkl = (const float*)d_in[6];  const float* bkl = (const float*)d_in[7];
    const float* Wqr = (const float*)d_in[8];  const float* bqr = (const float*)d_in[9];
    const float* Wkr = (const float*)d_in[10]; const float* bkr = (const float*)d_in[11];
    const float* Wq  = (const float*)d_in[12]; const float* bq  = (const float*)d_in[13];
    const float* Wk  = (const float*)d_in[14]; const float* bk  = (const float*)d_in[15];

    float* out = (float*)d_out;
    float* lossp = out + NELEM;

    // workspace layout (u16 elements): WTh[6*WSZ] WTl[6*WSZ] Ph[6*NPROJ] Pl[4*NPROJ]
    u16* ws16 = (u16*)d_ws;
    u16* WTh = ws16;
    u16* WTl = WTh + (size_t)6 * WSZ;
    u16* Ph  = WTl + (size_t)6 * WSZ;
    u16* Pl  = Ph + (size_t)6 * NPROJ;

    init_loss_kernel<<<dim3(1), dim3(64), 0, stream>>>(lossp);

    cast_wT<<<dim3(24, 24, 6), dim3(256), 0, stream>>>(
        Wql, Wkl, Wqr, Wkr, Wq, Wk, WTh, WTl);

    proj_gemm_mfma<<<dim3(DD / 128, NTOK / 128, 6), dim3(256), 0, stream>>>(
        query, key_t, WTh, WTl,
        bql, bkl, bqr, bkr, bq, bk, Ph, Pl);

    attn_mfma<<<dim3(96 * 32), dim3(512), 0, stream>>>(
        Ph, Pl, mask, span, out, lossp);
}

// Round 3
// 483.742 us; speedup vs baseline: 2.0775x; 1.3368x over previous
//
#include <hip/hip_runtime.h>
#include <math.h>

#define BB 8
#define SS 512
#define DD 768
#define HH 12
#define DKK 64
#define NTOK (BB*SS)                       // 4096
#define NELEM (25165824ull)                // B*H*S*S
#define NPROJ 3145728                      // 4096*768 elements per projection
#define WSZ   589824                       // 768*768
#define SCALEQ 0.03608439182435161f        // 1/sqrt(768)

typedef unsigned short u16;
typedef short short8 __attribute__((ext_vector_type(8)));
typedef float f32x4 __attribute__((ext_vector_type(4)));
typedef unsigned short u16x4 __attribute__((ext_vector_type(4)));

#define MFMA16 __builtin_amdgcn_mfma_f32_16x16x32_bf16

__device__ inline u16 f32_to_bf16(float f) {
    unsigned int u = __float_as_uint(f);
    unsigned int r = u + 0x7fffu + ((u >> 16) & 1u);   // RNE
    return (u16)(r >> 16);
}
__device__ inline float bf16_to_f32(u16 h) {
    return __uint_as_float(((unsigned int)h) << 16);
}

// async global->LDS, 16B per lane; LDS dst = wave-uniform base + lane*16
__device__ __forceinline__ void gld16(const u16* g, u16* l) {
    __builtin_amdgcn_global_load_lds(
        (const __attribute__((address_space(1))) unsigned int*)g,
        (__attribute__((address_space(3))) unsigned int*)l, 16, 0, 0);
}

__global__ __launch_bounds__(64)
void init_loss_kernel(float* lossp) {
    if (threadIdx.x == 0) *lossp = 0.0f;
}

// ---------------------------------------------------------------------------
// Transpose + split-cast the 6 weight matrices: W[768][768] f32 ->
// WT_hi/WT_lo[768][768] bf16 with WT[n][k] = W[k][n].
// ---------------------------------------------------------------------------
__global__ __launch_bounds__(256)
void cast_wT(const float* __restrict__ W0, const float* __restrict__ W1,
             const float* __restrict__ W2, const float* __restrict__ W3,
             const float* __restrict__ W4, const float* __restrict__ W5,
             u16* __restrict__ WTh, u16* __restrict__ WTl)
{
    __shared__ float tile[32][33];
    const int z = blockIdx.z;
    const float* W;
    switch (z) {
        case 0: W = W0; break; case 1: W = W1; break; case 2: W = W2; break;
        case 3: W = W3; break; case 4: W = W4; break; default: W = W5; break;
    }
    u16* th = WTh + (size_t)z * WSZ;
    u16* tl = WTl + (size_t)z * WSZ;
    const int t = threadIdx.x;
    const int k0 = blockIdx.y * 32, n0 = blockIdx.x * 32;
    const int rr = t >> 3, c0 = (t & 7) * 4;

    float4 v = *(const float4*)(W + (size_t)(k0 + rr) * DD + n0 + c0);
    tile[rr][c0 + 0] = v.x; tile[rr][c0 + 1] = v.y;
    tile[rr][c0 + 2] = v.z; tile[rr][c0 + 3] = v.w;
    __syncthreads();

    u16x4 hw, lw;
#pragma unroll
    for (int i = 0; i < 4; ++i) {
        float f = tile[c0 + i][rr];
        u16 hi = f32_to_bf16(f);
        hw[i] = hi;
        lw[i] = f32_to_bf16(f - bf16_to_f32(hi));
    }
    size_t o = (size_t)(n0 + rr) * DD + k0 + c0;
    *(u16x4*)&th[o] = hw;
    *(u16x4*)&tl[o] = lw;
}

// ---------------------------------------------------------------------------
// Split-cast X (query,key): f32 -> hi/lo bf16 flat buffers. (big-ws path)
// ---------------------------------------------------------------------------
__global__ __launch_bounds__(256)
void cast_X(const float* __restrict__ query, const float* __restrict__ key,
            u16* __restrict__ Xh, u16* __restrict__ Xl)
{
    const float* src = blockIdx.y ? key : query;
    u16* dh = Xh + (size_t)blockIdx.y * NPROJ;
    u16* dl = Xl + (size_t)blockIdx.y * NPROJ;
    size_t i0 = ((size_t)blockIdx.x * 256 + threadIdx.x) * 8;
    float f[8];
    *(float4*)&f[0] = *(const float4*)(src + i0);
    *(float4*)&f[4] = *(const float4*)(src + i0 + 4);
    short8 h, l;
#pragma unroll
    for (int i = 0; i < 8; ++i) {
        u16 hi = f32_to_bf16(f[i]);
        h[i] = (short)hi;
        l[i] = (short)f32_to_bf16(f[i] - bf16_to_f32(hi));
    }
    *(short8*)&dh[i0] = h;
    *(short8*)&dl[i0] = l;
}

// ---------------------------------------------------------------------------
// Projection GEMM, all-bf16 inputs, global_load_lds staging (big-ws path).
// 128x128 tile, BK=32, 256 threads (4 waves, each 64x64), 3-term bf16x3.
// ---------------------------------------------------------------------------
__global__ __launch_bounds__(256)
void proj_gemm_gld(const u16* __restrict__ Xh, const u16* __restrict__ Xl,
                   const u16* __restrict__ WTh, const u16* __restrict__ WTl,
                   const float* __restrict__ b0, const float* __restrict__ b1,
                   const float* __restrict__ b2, const float* __restrict__ b3,
                   const float* __restrict__ b4, const float* __restrict__ b5,
                   u16* __restrict__ Ph, u16* __restrict__ Pl)
{
    __shared__ alignas(16) u16 Ash[128][32];   // unpadded: gld16 requires contiguity
    __shared__ alignas(16) u16 Asl[128][32];
    __shared__ alignas(16) u16 Bsh[128][32];
    __shared__ alignas(16) u16 Bsl[128][32];

    const int z = blockIdx.z;
    const float* bias;
    switch (z) {
        case 0: bias = b0; break; case 1: bias = b1; break; case 2: bias = b2; break;
        case 3: bias = b3; break; case 4: bias = b4; break; default: bias = b5; break;
    }
    const float scl = (z & 1) ? 1.0f : SCALEQ;
    const u16* Ah_g = Xh + (size_t)(z & 1) * NPROJ;
    const u16* Al_g = Xl + (size_t)(z & 1) * NPROJ;
    const u16* WThz = WTh + (size_t)z * WSZ;
    const u16* WTlz = WTl + (size_t)z * WSZ;
    u16* Ch = Ph + (size_t)z * NPROJ;
    u16* Cl = Pl + (size_t)z * NPROJ;
    const bool wlo = (z < 4);

    const int t = threadIdx.x;
    const int w = t >> 6, l = t & 63, quad = l >> 4, ln = l & 15;
    const int m0 = blockIdx.y * 128, n0 = blockIdx.x * 128;
    const int wm = (w & 1) * 64, wn = (w >> 1) * 64;

    // staging geometry: wave w, pass p stages tile rows p*64+w*16 .. +16;
    // lane l -> row +(l>>2), col (l&3)*8 u16  == LDS offset lane*16B (contiguous)
    const int srow = w * 16 + (l >> 2);
    const int scol = (l & 3) * 8;
    const u16* gAh = Ah_g + (size_t)(m0 + srow) * DD + scol;
    const u16* gAl = Al_g + (size_t)(m0 + srow) * DD + scol;
    const u16* gBh = WThz + (size_t)(n0 + srow) * DD + scol;
    const u16* gBl = WTlz + (size_t)(n0 + srow) * DD + scol;
    u16* lAh0 = &Ash[w * 16][0];      u16* lAh1 = &Ash[w * 16 + 64][0];
    u16* lAl0 = &Asl[w * 16][0];      u16* lAl1 = &Asl[w * 16 + 64][0];
    u16* lBh0 = &Bsh[w * 16][0];      u16* lBh1 = &Bsh[w * 16 + 64][0];
    u16* lBl0 = &Bsl[w * 16][0];      u16* lBl1 = &Bsl[w * 16 + 64][0];
    const size_t rstep = (size_t)64 * DD;

    f32x4 acc[4][4];
#pragma unroll
    for (int i = 0; i < 4; ++i)
#pragma unroll
        for (int jj = 0; jj < 4; ++jj) acc[i][jj] = (f32x4){0.f, 0.f, 0.f, 0.f};

    for (int k0 = 0; k0 < DD; k0 += 32) {
        gld16(gAh + k0, lAh0);  gld16(gAh + k0 + rstep, lAh1);
        gld16(gAl + k0, lAl0);  gld16(gAl + k0 + rstep, lAl1);
        gld16(gBh + k0, lBh0);  gld16(gBh + k0 + rstep, lBh1);
        gld16(gBl + k0, lBl0);  gld16(gBl + k0 + rstep, lBl1);
        __syncthreads();

        short8 afh[4], afl[4], bfh[4], bfl[4];
#pragma unroll
        for (int mt = 0; mt < 4; ++mt) {
            afh[mt] = *(const short8*)&Ash[wm + mt * 16 + ln][quad * 8];
            afl[mt] = *(const short8*)&Asl[wm + mt * 16 + ln][quad * 8];
        }
#pragma unroll
        for (int nt = 0; nt < 4; ++nt) {
            bfh[nt] = *(const short8*)&Bsh[wn + nt * 16 + ln][quad * 8];
            bfl[nt] = *(const short8*)&Bsl[wn + nt * 16 + ln][quad * 8];
        }
#pragma unroll
        for (int mt = 0; mt < 4; ++mt)
#pragma unroll
            for (int nt = 0; nt < 4; ++nt) {
                acc[mt][nt] = MFMA16(afh[mt], bfh[nt], acc[mt][nt], 0, 0, 0);
                acc[mt][nt] = MFMA16(afh[mt], bfl[nt], acc[mt][nt], 0, 0, 0);
                acc[mt][nt] = MFMA16(afl[mt], bfh[nt], acc[mt][nt], 0, 0, 0);
            }
        __syncthreads();
    }

#pragma unroll
    for (int nt = 0; nt < 4; ++nt) {
        const int n = n0 + wn + nt * 16 + ln;
        const float bv = bias[n];
#pragma unroll
        for (int mt = 0; mt < 4; ++mt) {
            const int mbase = m0 + wm + mt * 16 + quad * 4;
#pragma unroll
            for (int reg = 0; reg < 4; ++reg) {
                float c = (acc[mt][nt][reg] + bv) * scl;
                u16 hi = f32_to_bf16(c);
                size_t o = (size_t)(mbase + reg) * DD + n;
                Ch[o] = hi;
                if (wlo) Cl[o] = f32_to_bf16(c - bf16_to_f32(hi));
            }
        }
    }
}

// ---------------------------------------------------------------------------
// Fallback projection GEMM (round-2, f32 A staged in-kernel). small-ws path.
// ---------------------------------------------------------------------------
__global__ __launch_bounds__(256)
void proj_gemm_mfma(const float* __restrict__ query, const float* __restrict__ key,
                    const u16* __restrict__ WTh, const u16* __restrict__ WTl,
                    const float* __restrict__ b0, const float* __restrict__ b1,
                    const float* __restrict__ b2, const float* __restrict__ b3,
                    const float* __restrict__ b4, const float* __restrict__ b5,
                    u16* __restrict__ Ph, u16* __restrict__ Pl)
{
    __shared__ alignas(16) u16 Ash[128][40];
    __shared__ alignas(16) u16 Asl[128][40];
    __shared__ alignas(16) u16 Bsh[128][40];
    __shared__ alignas(16) u16 Bsl[128][40];

    const int z = blockIdx.z;
    const float* X = (z & 1) ? key : query;
    const float* bias;
    switch (z) {
        case 0: bias = b0; break; case 1: bias = b1; break; case 2: bias = b2; break;
        case 3: bias = b3; break; case 4: bias = b4; break; default: bias = b5; break;
    }
    const float scl = (z & 1) ? 1.0f : SCALEQ;
    const u16* WThz = WTh + (size_t)z * WSZ;
    const u16* WTlz = WTl + (size_t)z * WSZ;
    u16* Ch = Ph + (size_t)z * NPROJ;
    u16* Cl = Pl + (size_t)z * NPROJ;
    const bool wlo = (z < 4);

    const int t = threadIdx.x;
    const int w = t >> 6, l = t & 63, quad = l >> 4, ln = l & 15;
    const int m0 = blockIdx.y * 128, n0 = blockIdx.x * 128;
    const int wm = (w & 1) * 64, wn = (w >> 1) * 64;

    const int arow = t >> 1, akoff = (t & 1) * 16;
    const int brow = t >> 1, bkoff = (t & 1) * 16;

    f32x4 acc[4][4];
#pragma unroll
    for (int i = 0; i < 4; ++i)
#pragma unroll
        for (int jj = 0; jj < 4; ++jj) acc[i][jj] = (f32x4){0.f, 0.f, 0.f, 0.f};

    for (int k0 = 0; k0 < DD; k0 += 32) {
        {
            const float* asrc = X + (size_t)(m0 + arow) * DD + k0 + akoff;
            float fa[16];
            *(float4*)&fa[0]  = *(const float4*)(asrc + 0);
            *(float4*)&fa[4]  = *(const float4*)(asrc + 4);
            *(float4*)&fa[8]  = *(const float4*)(asrc + 8);
            *(float4*)&fa[12] = *(const float4*)(asrc + 12);
            short8 h0, h1, l0, l1;
#pragma unroll
            for (int i = 0; i < 8; ++i) {
                u16 hi = f32_to_bf16(fa[i]);
                h0[i] = (short)hi;
                l0[i] = (short)f32_to_bf16(fa[i] - bf16_to_f32(hi));
                u16 hi2 = f32_to_bf16(fa[8 + i]);
                h1[i] = (short)hi2;
                l1[i] = (short)f32_to_bf16(fa[8 + i] - bf16_to_f32(hi2));
            }
            *(short8*)&Ash[arow][akoff]     = h0;
            *(short8*)&Ash[arow][akoff + 8] = h1;
            *(short8*)&Asl[arow][akoff]     = l0;
            *(short8*)&Asl[arow][akoff + 8] = l1;
        }
        {
            const u16* bh = WThz + (size_t)(n0 + brow) * DD + k0 + bkoff;
            const u16* bl = WTlz + (size_t)(n0 + brow) * DD + k0 + bkoff;
            *(uint4*)&Bsh[brow][bkoff]     = *(const uint4*)(bh);
            *(uint4*)&Bsh[brow][bkoff + 8] = *(const uint4*)(bh + 8);
            *(uint4*)&Bsl[brow][bkoff]     = *(const uint4*)(bl);
            *(uint4*)&Bsl[brow][bkoff + 8] = *(const uint4*)(bl + 8);
        }
        __syncthreads();

        short8 afh[4], afl[4], bfh[4], bfl[4];
#pragma unroll
        for (int mt = 0; mt < 4; ++mt) {
            afh[mt] = *(const short8*)&Ash[wm + mt * 16 + ln][quad * 8];
            afl[mt] = *(const short8*)&Asl[wm + mt * 16 + ln][quad * 8];
        }
#pragma unroll
        for (int nt = 0; nt < 4; ++nt) {
            bfh[nt] = *(const short8*)&Bsh[wn + nt * 16 + ln][quad * 8];
            bfl[nt] = *(const short8*)&Bsl[wn + nt * 16 + ln][quad * 8];
        }
#pragma unroll
        for (int mt = 0; mt < 4; ++mt)
#pragma unroll
            for (int nt = 0; nt < 4; ++nt) {
                acc[mt][nt] = MFMA16(afh[mt], bfh[nt], acc[mt][nt], 0, 0, 0);
                acc[mt][nt] = MFMA16(afh[mt], bfl[nt], acc[mt][nt], 0, 0, 0);
                acc[mt][nt] = MFMA16(afl[mt], bfh[nt], acc[mt][nt], 0, 0, 0);
            }
        __syncthreads();
    }

#pragma unroll
    for (int nt = 0; nt < 4; ++nt) {
        const int n = n0 + wn + nt * 16 + ln;
        const float bv = bias[n];
#pragma unroll
        for (int mt = 0; mt < 4; ++mt) {
            const int mbase = m0 + wm + mt * 16 + quad * 4;
#pragma unroll
            for (int reg = 0; reg < 4; ++reg) {
                float c = (acc[mt][nt][reg] + bv) * scl;
                u16 hi = f32_to_bf16(c);
                size_t o = (size_t)(mbase + reg) * DD + n;
                Ch[o] = hi;
                if (wlo) Cl[o] = f32_to_bf16(c - bf16_to_f32(hi));
            }
        }
    }
}

// ---------------------------------------------------------------------------
// Attention: one block per (b,h, 16-row q-tile). 512 threads (8 waves).
// smb held in registers (16/thread) -> LDS ~74.5 KB -> 2 blocks/CU.
// ---------------------------------------------------------------------------
#define CHK 128
__global__ __launch_bounds__(512, 4)
void attn_mfma(const u16* __restrict__ Ph, const u16* __restrict__ Pl,
               const float* __restrict__ mask, const float* __restrict__ span,
               float* __restrict__ outp, float* __restrict__ lossp)
{
    __shared__ alignas(16) u16 Kth[CHK][72];
    __shared__ alignas(16) u16 Ktl[CHK][72];
    __shared__ alignas(16) u16 Qsh[16][72];
    __shared__ alignas(16) u16 Qsl[16][72];
    __shared__ float curb[16][516];
    __shared__ float lred[8];

    const int t = threadIdx.x;
    const int blk = blockIdx.x;
    const int qt = blk & 31;
    const int bh = blk >> 5;
    const int b = bh / HH, h = bh % HH;
    const int w = t >> 6, l = t & 63, quad = l >> 4, ln = l & 15;
    const int r = t >> 5, j = t & 31;
    const int qrow = qt * 16 + r;

    float smbr[16];   // soft mask, registers (row-op mapping owns (r, c=u*32+j))

    auto compute_scores = [&](const u16* Qh, const u16* Ql,
                              const u16* Kh, const u16* Kl, bool use_lo) {
        __syncthreads();
        if (t < 256) {
            int which = t >> 7, tt = t & 127;
            int row = tt >> 3, co = (tt & 7) * 8;
            if (!which) {
                const u16* src = Qh + (size_t)(b * SS + qt * 16 + row) * DD + h * DKK + co;
                *(uint4*)&Qsh[row][co] = *(const uint4*)src;
            } else if (use_lo) {
                const u16* src = Ql + (size_t)(b * SS + qt * 16 + row) * DD + h * DKK + co;
                *(uint4*)&Qsl[row][co] = *(const uint4*)src;
            }
        }
        __syncthreads();
        short8 ah0 = *(const short8*)&Qsh[ln][quad * 8];
        short8 ah1 = *(const short8*)&Qsh[ln][32 + quad * 8];
        short8 al0 = ah0, al1 = ah1;
        if (use_lo) {
            al0 = *(const short8*)&Qsl[ln][quad * 8];
            al1 = *(const short8*)&Qsl[ln][32 + quad * 8];
        }
        for (int kc = 0; kc < SS / CHK; ++kc) {
            {
                int row = t >> 2, co = (t & 3) * 16;
                const u16* src = Kh + (size_t)(b * SS + kc * CHK + row) * DD + h * DKK + co;
                *(uint4*)&Kth[row][co]     = *(const uint4*)(src);
                *(uint4*)&Kth[row][co + 8] = *(const uint4*)(src + 8);
                if (use_lo) {
                    const u16* src2 = Kl + (size_t)(b * SS + kc * CHK + row) * DD + h * DKK + co;
                    *(uint4*)&Ktl[row][co]     = *(const uint4*)(src2);
                    *(uint4*)&Ktl[row][co + 8] = *(const uint4*)(src2 + 8);
                }
            }
            __syncthreads();
            const int nb = w * 16;
            short8 bh0 = *(const short8*)&Kth[nb + ln][quad * 8];
            short8 bh1 = *(const short8*)&Kth[nb + ln][32 + quad * 8];
            f32x4 acc = (f32x4){0.f, 0.f, 0.f, 0.f};
            acc = MFMA16(ah0, bh0, acc, 0, 0, 0);
            acc = MFMA16(ah1, bh1, acc, 0, 0, 0);
            if (use_lo) {
                short8 bl0 = *(const short8*)&Ktl[nb + ln][quad * 8];
                short8 bl1 = *(const short8*)&Ktl[nb + ln][32 + quad * 8];
                acc = MFMA16(ah0, bl0, acc, 0, 0, 0);
                acc = MFMA16(ah1, bl1, acc, 0, 0, 0);
                acc = MFMA16(al0, bh0, acc, 0, 0, 0);
                acc = MFMA16(al1, bh1, acc, 0, 0, 0);
            }
            const int cbase = kc * CHK + nb + ln;
#pragma unroll
            for (int reg = 0; reg < 4; ++reg)
                curb[quad * 4 + reg][cbase] = acc[reg];
            __syncthreads();
        }
    };

    // ---------------- Stage L ----------------
    compute_scores(Ph + 0 * (size_t)NPROJ, Pl + 0 * (size_t)NPROJ,
                   Ph + 1 * (size_t)NPROJ, Pl + 1 * (size_t)NPROJ, true);
    {
        float e[16];
        float mx = -3.0e38f;
#pragma unroll
        for (int u = 0; u < 16; ++u) {
            int c = u * 32 + j;
            float v = curb[r][c];
            if (c <= qrow && v > mx) mx = v;
        }
#pragma unroll
        for (int off = 16; off >= 1; off >>= 1) mx = fmaxf(mx, __shfl_xor(mx, off));
        float sum = 0.0f;
#pragma unroll
        for (int u = 0; u < 16; ++u) {
            int c = u * 32 + j;
            float v = (c <= qrow) ? __expf(curb[r][c] - mx) : 0.0f;
            e[u] = v; sum += v;
        }
#pragma unroll
        for (int off = 16; off >= 1; off >>= 1) sum += __shfl_xor(sum, off);
        float inv = 1.0f / sum;
        float run = 0.0f;
#pragma unroll
        for (int u = 0; u < 16; ++u) {
            float sc = e[u];
#pragma unroll
            for (int off = 1; off < 32; off <<= 1) {
                float ww = __shfl_up(sc, off, 32);
                if (j >= off) sc += ww;
            }
            smbr[u] = (run + sc) * inv;
            run += __shfl(sc, 31, 32);
        }
    }

    // ---------------- Stage R ----------------
    compute_scores(Ph + 2 * (size_t)NPROJ, Pl + 2 * (size_t)NPROJ,
                   Ph + 3 * (size_t)NPROJ, Pl + 3 * (size_t)NPROJ, true);
    {
        float e[16];
        float mx = -3.0e38f;
#pragma unroll
        for (int u = 0; u < 16; ++u) {
            int c = u * 32 + j;
            float v = curb[r][c];
            if (c >= qrow && v > mx) mx = v;
        }
#pragma unroll
        for (int off = 16; off >= 1; off >>= 1) mx = fmaxf(mx, __shfl_xor(mx, off));
        float sum = 0.0f;
#pragma unroll
        for (int u = 0; u < 16; ++u) {
            int c = u * 32 + j;
            float v = (c >= qrow) ? __expf(curb[r][c] - mx) : 0.0f;
            e[u] = v; sum += v;
        }
#pragma unroll
        for (int off = 16; off >= 1; off >>= 1) sum += __shfl_xor(sum, off);
        float inv = 1.0f / sum;
        float run = 0.0f;
#pragma unroll
        for (int u = 15; u >= 0; --u) {
            float sc = e[u];
#pragma unroll
            for (int off = 1; off < 32; off <<= 1) {
                float ww = __shfl_down(sc, off, 32);
                if (j + off < 32) sc += ww;
            }
            smbr[u] *= (run + sc) * inv;
            run += __shfl(sc, 0, 32);
        }
    }

    // ---------------- Stage M ----------------
    compute_scores(Ph + 4 * (size_t)NPROJ, (const u16*)0,
                   Ph + 5 * (size_t)NPROJ, (const u16*)0, false);
    {
        float mv  = mask[b * SS + qrow];
        float rmq = (mv == -10000.0f) ? 1.0e9f : mv;
        float vb[16];
        float mx = -3.0e38f;
#pragma unroll
        for (int u = 0; u < 16; ++u) {
            int c = u * 32 + j;
            float mk  = mask[b * SS + c];
            float rmk = (mk == -10000.0f) ? 1.0e9f : mk;
            float v = (curb[r][c] - rmq - rmk) * smbr[u];
            vb[u] = v;
            mx = fmaxf(mx, v);
        }
#pragma unroll
        for (int off = 16; off >= 1; off >>= 1) mx = fmaxf(mx, __shfl_xor(mx, off));
        float sum = 0.0f;
#pragma unroll
        for (int u = 0; u < 16; ++u) {
            float ev = __expf(vb[u] - mx);
            vb[u] = ev; sum += ev;
        }
#pragma unroll
        for (int off = 16; off >= 1; off >>= 1) sum += __shfl_xor(sum, off);
        float inv = 1.0f / sum;

        float* orow = outp + (((size_t)(b * HH + h) * SS + qrow)) * SS;
        const float* sprow = span + (((size_t)(h * BB + b) * SS + qrow)) * SS;
        float lsum = 0.0f;
#pragma unroll
        for (int u = 0; u < 16; ++u) {
            int c = u * 32 + j;
            float p = vb[u] * inv;
            orow[c] = p;
            float s = sprow[c];
            lsum += __logf(1.0f + __expf(-p)) + (1.0f - s) * p;
        }
#pragma unroll
        for (int off = 32; off >= 1; off >>= 1) lsum += __shfl_xor(lsum, off);
        if ((t & 63) == 0) lred[t >> 6] = lsum;
        __syncthreads();
        if (t == 0) {
            float tot = 0.0f;
#pragma unroll
            for (int i = 0; i < 8; ++i) tot += lred[i];
            atomicAdd(lossp, tot * (float)(1.0 / 25165824.0));
        }
    }
}

extern "C" void kernel_launch(void* const* d_in, const int* in_sizes, int n_in,
                              void* d_out, int out_size, void* d_ws, size_t ws_size,
                              hipStream_t stream)
{
    const float* query = (const float*)d_in[0];
    const float* key_t = (const float*)d_in[1];
    const float* mask  = (const float*)d_in[2];
    const float* span  = (const float*)d_in[3];
    const float* Wql = (const float*)d_in[4];  const float* bql = (const float*)d_in[5];
    const float* Wkl = (const float*)d_in[6];  const float* bkl = (const float*)d_in[7];
    const float* Wqr = (const float*)d_in[8];  const float* bqr = (const float*)d_in[9];
    const float* Wkr = (const float*)d_in[10]; const float* bkr = (const float*)d_in[11];
    const float* Wq  = (const float*)d_in[12]; const float* bq  = (const float*)d_in[13];
    const float* Wk  = (const float*)d_in[14]; const float* bk  = (const float*)d_in[15];

    float* out = (float*)d_out;
    float* lossp = out + NELEM;

    // ws layout (u16): WTh[6W] WTl[6W] Ph[6P] Pl[4P] | Xh[2P] Xl[2P] (big-ws only)
    u16* ws16 = (u16*)d_ws;
    u16* WTh = ws16;
    u16* WTl = WTh + (size_t)6 * WSZ;
    u16* Ph  = WTl + (size_t)6 * WSZ;
    u16* Pl  = Ph + (size_t)6 * NPROJ;
    u16* Xh  = Pl + (size_t)4 * NPROJ;
    u16* Xl  = Xh + (size_t)2 * NPROJ;
    const size_t need_big = ((size_t)12 * WSZ + (size_t)14 * NPROJ) * 2;  // 102.24 MB
    const bool bigws = ws_size >= need_big;

    init_loss_kernel<<<dim3(1), dim3(64), 0, stream>>>(lossp);

    cast_wT<<<dim3(24, 24, 6), dim3(256), 0, stream>>>(
        Wql, Wkl, Wqr, Wkr, Wq, Wk, WTh, WTl);

    if (bigws) {
        cast_X<<<dim3(1536, 2), dim3(256), 0, stream>>>(query, key_t, Xh, Xl);
        proj_gemm_gld<<<dim3(DD / 128, NTOK / 128, 6), dim3(256), 0, stream>>>(
            Xh, Xl, WTh, WTl, bql, bkl, bqr, bkr, bq, bk, Ph, Pl);
    } else {
        proj_gemm_mfma<<<dim3(DD / 128, NTOK / 128, 6), dim3(256), 0, stream>>>(
            query, key_t, WTh, WTl, bql, bkl, bqr, bkr, bq, bk, Ph, Pl);
    }

    attn_mfma<<<dim3(96 * 32), dim3(512), 0, stream>>>(
        Ph, Pl, mask, span, out, lossp);
}

// Round 4
// 455.673 us; speedup vs baseline: 2.2055x; 1.0616x over previous
//
#include <hip/hip_runtime.h>
#include <math.h>

#define BB 8
#define SS 512
#define DD 768
#define HH 12
#define DKK 64
#define NTOK (BB*SS)                       // 4096
#define NELEM (25165824ull)                // B*H*S*S
#define NPROJ 3145728                      // 4096*768 elements per projection
#define WSZ   589824                       // 768*768
#define SCALEQ 0.03608439182435161f        // 1/sqrt(768)

typedef unsigned short u16;
typedef short short8 __attribute__((ext_vector_type(8)));
typedef float f32x4 __attribute__((ext_vector_type(4)));
typedef unsigned short u16x4 __attribute__((ext_vector_type(4)));

#define MFMA16 __builtin_amdgcn_mfma_f32_16x16x32_bf16

__device__ inline u16 f32_to_bf16(float f) {
    unsigned int u = __float_as_uint(f);
    unsigned int r = u + 0x7fffu + ((u >> 16) & 1u);   // RNE
    return (u16)(r >> 16);
}
__device__ inline float bf16_to_f32(u16 h) {
    return __uint_as_float(((unsigned int)h) << 16);
}

// async global->LDS, 16B per lane; LDS dst = wave-uniform base + lane*16
__device__ __forceinline__ void gld16(const u16* g, u16* l) {
    __builtin_amdgcn_global_load_lds(
        (const __attribute__((address_space(1))) unsigned int*)g,
        (__attribute__((address_space(3))) unsigned int*)l, 16, 0, 0);
}

// ---------------------------------------------------------------------------
// Transpose + split-cast the 6 weight matrices; block (0,0,0) zeroes loss.
// ---------------------------------------------------------------------------
__global__ __launch_bounds__(256)
void cast_wT(const float* __restrict__ W0, const float* __restrict__ W1,
             const float* __restrict__ W2, const float* __restrict__ W3,
             const float* __restrict__ W4, const float* __restrict__ W5,
             u16* __restrict__ WTh, u16* __restrict__ WTl,
             float* __restrict__ lossp)
{
    __shared__ float tile[32][33];
    if (blockIdx.x == 0 && blockIdx.y == 0 && blockIdx.z == 0 && threadIdx.x == 0)
        *lossp = 0.0f;
    const int z = blockIdx.z;
    const float* W;
    switch (z) {
        case 0: W = W0; break; case 1: W = W1; break; case 2: W = W2; break;
        case 3: W = W3; break; case 4: W = W4; break; default: W = W5; break;
    }
    u16* th = WTh + (size_t)z * WSZ;
    u16* tl = WTl + (size_t)z * WSZ;
    const int t = threadIdx.x;
    const int k0 = blockIdx.y * 32, n0 = blockIdx.x * 32;
    const int rr = t >> 3, c0 = (t & 7) * 4;

    float4 v = *(const float4*)(W + (size_t)(k0 + rr) * DD + n0 + c0);
    tile[rr][c0 + 0] = v.x; tile[rr][c0 + 1] = v.y;
    tile[rr][c0 + 2] = v.z; tile[rr][c0 + 3] = v.w;
    __syncthreads();

    u16x4 hw, lw;
#pragma unroll
    for (int i = 0; i < 4; ++i) {
        float f = tile[c0 + i][rr];
        u16 hi = f32_to_bf16(f);
        hw[i] = hi;
        lw[i] = f32_to_bf16(f - bf16_to_f32(hi));
    }
    size_t o = (size_t)(n0 + rr) * DD + k0 + c0;
    *(u16x4*)&th[o] = hw;
    *(u16x4*)&tl[o] = lw;
}

// ---------------------------------------------------------------------------
// Split-cast X (query,key): f32 -> hi/lo bf16 flat buffers.
// ---------------------------------------------------------------------------
__global__ __launch_bounds__(256)
void cast_X(const float* __restrict__ query, const float* __restrict__ key,
            u16* __restrict__ Xh, u16* __restrict__ Xl)
{
    const float* src = blockIdx.y ? key : query;
    u16* dh = Xh + (size_t)blockIdx.y * NPROJ;
    u16* dl = Xl + (size_t)blockIdx.y * NPROJ;
    size_t i0 = ((size_t)blockIdx.x * 256 + threadIdx.x) * 8;
    float f[8];
    *(float4*)&f[0] = *(const float4*)(src + i0);
    *(float4*)&f[4] = *(const float4*)(src + i0 + 4);
    short8 h, l;
#pragma unroll
    for (int i = 0; i < 8; ++i) {
        u16 hi = f32_to_bf16(f[i]);
        h[i] = (short)hi;
        l[i] = (short)f32_to_bf16(f[i] - bf16_to_f32(hi));
    }
    *(short8*)&dh[i0] = h;
    *(short8*)&dl[i0] = l;
}

// ---------------------------------------------------------------------------
// Projection GEMM v2: operand-swapped MFMA (lane acc = 4 consecutive n)
// -> packed u16x4 stores. z<4: 3-term bf16x3 hi/lo out; z>=4: hi-only 1-term.
// 128x128 tile, BK=32, 256 threads (4 waves), global_load_lds staging.
// ---------------------------------------------------------------------------
__global__ __launch_bounds__(256)
void proj_gemm_gld(const u16* __restrict__ Xh, const u16* __restrict__ Xl,
                   const u16* __restrict__ WTh, const u16* __restrict__ WTl,
                   const float* __restrict__ b0, const float* __restrict__ b1,
                   const float* __restrict__ b2, const float* __restrict__ b3,
                   const float* __restrict__ b4, const float* __restrict__ b5,
                   u16* __restrict__ Ph, u16* __restrict__ Pl)
{
    __shared__ alignas(16) u16 Ash[128][32];   // unpadded: gld16 requires contiguity
    __shared__ alignas(16) u16 Asl[128][32];
    __shared__ alignas(16) u16 Bsh[128][32];
    __shared__ alignas(16) u16 Bsl[128][32];

    const int z = blockIdx.z;
    const float* bias;
    switch (z) {
        case 0: bias = b0; break; case 1: bias = b1; break; case 2: bias = b2; break;
        case 3: bias = b3; break; case 4: bias = b4; break; default: bias = b5; break;
    }
    const float scl = (z & 1) ? 1.0f : SCALEQ;
    const u16* Ah_g = Xh + (size_t)(z & 1) * NPROJ;
    const u16* Al_g = Xl + (size_t)(z & 1) * NPROJ;
    const u16* WThz = WTh + (size_t)z * WSZ;
    const u16* WTlz = WTl + (size_t)z * WSZ;
    u16* Ch = Ph + (size_t)z * NPROJ;
    u16* Cl = Pl + (size_t)z * NPROJ;
    const bool wlo = (z < 4);

    const int t = threadIdx.x;
    const int w = t >> 6, l = t & 63, quad = l >> 4, ln = l & 15;
    const int m0 = blockIdx.y * 128, n0 = blockIdx.x * 128;
    const int wm = (w & 1) * 64, wn = (w >> 1) * 64;

    const int srow = w * 16 + (l >> 2);
    const int scol = (l & 3) * 8;
    const u16* gAh = Ah_g + (size_t)(m0 + srow) * DD + scol;
    const u16* gAl = Al_g + (size_t)(m0 + srow) * DD + scol;
    const u16* gBh = WThz + (size_t)(n0 + srow) * DD + scol;
    const u16* gBl = WTlz + (size_t)(n0 + srow) * DD + scol;
    u16* lAh0 = &Ash[w * 16][0];      u16* lAh1 = &Ash[w * 16 + 64][0];
    u16* lAl0 = &Asl[w * 16][0];      u16* lAl1 = &Asl[w * 16 + 64][0];
    u16* lBh0 = &Bsh[w * 16][0];      u16* lBh1 = &Bsh[w * 16 + 64][0];
    u16* lBl0 = &Bsl[w * 16][0];      u16* lBl1 = &Bsl[w * 16 + 64][0];
    const size_t rstep = (size_t)64 * DD;

    f32x4 acc[4][4];   // acc[mt][nt]; lane holds n = wn+nt*16+quad*4+reg, m = wm+mt*16+ln
#pragma unroll
    for (int i = 0; i < 4; ++i)
#pragma unroll
        for (int jj = 0; jj < 4; ++jj) acc[i][jj] = (f32x4){0.f, 0.f, 0.f, 0.f};

    for (int k0 = 0; k0 < DD; k0 += 32) {
        gld16(gAh + k0, lAh0);  gld16(gAh + k0 + rstep, lAh1);
        gld16(gBh + k0, lBh0);  gld16(gBh + k0 + rstep, lBh1);
        if (wlo) {
            gld16(gAl + k0, lAl0);  gld16(gAl + k0 + rstep, lAl1);
            gld16(gBl + k0, lBl0);  gld16(gBl + k0 + rstep, lBl1);
        }
        __syncthreads();

        short8 afh[4], afl[4], bfh[4], bfl[4];
#pragma unroll
        for (int mt = 0; mt < 4; ++mt)
            afh[mt] = *(const short8*)&Ash[wm + mt * 16 + ln][quad * 8];
#pragma unroll
        for (int nt = 0; nt < 4; ++nt)
            bfh[nt] = *(const short8*)&Bsh[wn + nt * 16 + ln][quad * 8];
        if (wlo) {
#pragma unroll
            for (int mt = 0; mt < 4; ++mt)
                afl[mt] = *(const short8*)&Asl[wm + mt * 16 + ln][quad * 8];
#pragma unroll
            for (int nt = 0; nt < 4; ++nt)
                bfl[nt] = *(const short8*)&Bsl[wn + nt * 16 + ln][quad * 8];
        }
        // operand-swapped: first operand indexes D's row dim (= n), second = m
#pragma unroll
        for (int mt = 0; mt < 4; ++mt)
#pragma unroll
            for (int nt = 0; nt < 4; ++nt) {
                acc[mt][nt] = MFMA16(bfh[nt], afh[mt], acc[mt][nt], 0, 0, 0);
                if (wlo) {
                    acc[mt][nt] = MFMA16(bfl[nt], afh[mt], acc[mt][nt], 0, 0, 0);
                    acc[mt][nt] = MFMA16(bfh[nt], afl[mt], acc[mt][nt], 0, 0, 0);
                }
            }
        __syncthreads();
    }

    // epilogue: lane stores 4 consecutive n as u16x4
#pragma unroll
    for (int nt = 0; nt < 4; ++nt) {
        const int nb4 = n0 + wn + nt * 16 + quad * 4;
        float4 bias4 = *(const float4*)(bias + nb4);
        float bv[4] = {bias4.x, bias4.y, bias4.z, bias4.w};
#pragma unroll
        for (int mt = 0; mt < 4; ++mt) {
            const int m = m0 + wm + mt * 16 + ln;
            u16x4 hv, lv;
#pragma unroll
            for (int reg = 0; reg < 4; ++reg) {
                float c = (acc[mt][nt][reg] + bv[reg]) * scl;
                u16 hi = f32_to_bf16(c);
                hv[reg] = hi;
                lv[reg] = f32_to_bf16(c - bf16_to_f32(hi));
            }
            size_t o = (size_t)m * DD + nb4;
            *(u16x4*)&Ch[o] = hv;
            if (wlo) *(u16x4*)&Cl[o] = lv;
        }
    }
}

// ---------------------------------------------------------------------------
// Fallback projection GEMM (round-2 style, f32 A staged in-kernel).
// ---------------------------------------------------------------------------
__global__ __launch_bounds__(256)
void proj_gemm_mfma(const float* __restrict__ query, const float* __restrict__ key,
                    const u16* __restrict__ WTh, const u16* __restrict__ WTl,
                    const float* __restrict__ b0, const float* __restrict__ b1,
                    const float* __restrict__ b2, const float* __restrict__ b3,
                    const float* __restrict__ b4, const float* __restrict__ b5,
                    u16* __restrict__ Ph, u16* __restrict__ Pl)
{
    __shared__ alignas(16) u16 Ash[128][40];
    __shared__ alignas(16) u16 Asl[128][40];
    __shared__ alignas(16) u16 Bsh[128][40];
    __shared__ alignas(16) u16 Bsl[128][40];

    const int z = blockIdx.z;
    const float* X = (z & 1) ? key : query;
    const float* bias;
    switch (z) {
        case 0: bias = b0; break; case 1: bias = b1; break; case 2: bias = b2; break;
        case 3: bias = b3; break; case 4: bias = b4; break; default: bias = b5; break;
    }
    const float scl = (z & 1) ? 1.0f : SCALEQ;
    const u16* WThz = WTh + (size_t)z * WSZ;
    const u16* WTlz = WTl + (size_t)z * WSZ;
    u16* Ch = Ph + (size_t)z * NPROJ;
    u16* Cl = Pl + (size_t)z * NPROJ;
    const bool wlo = (z < 4);

    const int t = threadIdx.x;
    const int w = t >> 6, l = t & 63, quad = l >> 4, ln = l & 15;
    const int m0 = blockIdx.y * 128, n0 = blockIdx.x * 128;
    const int wm = (w & 1) * 64, wn = (w >> 1) * 64;

    const int arow = t >> 1, akoff = (t & 1) * 16;
    const int brow = t >> 1, bkoff = (t & 1) * 16;

    f32x4 acc[4][4];
#pragma unroll
    for (int i = 0; i < 4; ++i)
#pragma unroll
        for (int jj = 0; jj < 4; ++jj) acc[i][jj] = (f32x4){0.f, 0.f, 0.f, 0.f};

    for (int k0 = 0; k0 < DD; k0 += 32) {
        {
            const float* asrc = X + (size_t)(m0 + arow) * DD + k0 + akoff;
            float fa[16];
            *(float4*)&fa[0]  = *(const float4*)(asrc + 0);
            *(float4*)&fa[4]  = *(const float4*)(asrc + 4);
            *(float4*)&fa[8]  = *(const float4*)(asrc + 8);
            *(float4*)&fa[12] = *(const float4*)(asrc + 12);
            short8 h0, h1, l0, l1;
#pragma unroll
            for (int i = 0; i < 8; ++i) {
                u16 hi = f32_to_bf16(fa[i]);
                h0[i] = (short)hi;
                l0[i] = (short)f32_to_bf16(fa[i] - bf16_to_f32(hi));
                u16 hi2 = f32_to_bf16(fa[8 + i]);
                h1[i] = (short)hi2;
                l1[i] = (short)f32_to_bf16(fa[8 + i] - bf16_to_f32(hi2));
            }
            *(short8*)&Ash[arow][akoff]     = h0;
            *(short8*)&Ash[arow][akoff + 8] = h1;
            *(short8*)&Asl[arow][akoff]     = l0;
            *(short8*)&Asl[arow][akoff + 8] = l1;
        }
        {
            const u16* bhp = WThz + (size_t)(n0 + brow) * DD + k0 + bkoff;
            const u16* blp = WTlz + (size_t)(n0 + brow) * DD + k0 + bkoff;
            *(uint4*)&Bsh[brow][bkoff]     = *(const uint4*)(bhp);
            *(uint4*)&Bsh[brow][bkoff + 8] = *(const uint4*)(bhp + 8);
            *(uint4*)&Bsl[brow][bkoff]     = *(const uint4*)(blp);
            *(uint4*)&Bsl[brow][bkoff + 8] = *(const uint4*)(blp + 8);
        }
        __syncthreads();

        short8 afh[4], afl[4], bfh[4], bfl[4];
#pragma unroll
        for (int mt = 0; mt < 4; ++mt) {
            afh[mt] = *(const short8*)&Ash[wm + mt * 16 + ln][quad * 8];
            afl[mt] = *(const short8*)&Asl[wm + mt * 16 + ln][quad * 8];
        }
#pragma unroll
        for (int nt = 0; nt < 4; ++nt) {
            bfh[nt] = *(const short8*)&Bsh[wn + nt * 16 + ln][quad * 8];
            bfl[nt] = *(const short8*)&Bsl[wn + nt * 16 + ln][quad * 8];
        }
#pragma unroll
        for (int mt = 0; mt < 4; ++mt)
#pragma unroll
            for (int nt = 0; nt < 4; ++nt) {
                acc[mt][nt] = MFMA16(bfh[nt], afh[mt], acc[mt][nt], 0, 0, 0);
                acc[mt][nt] = MFMA16(bfl[nt], afh[mt], acc[mt][nt], 0, 0, 0);
                acc[mt][nt] = MFMA16(bfh[nt], afl[mt], acc[mt][nt], 0, 0, 0);
            }
        __syncthreads();
    }

#pragma unroll
    for (int nt = 0; nt < 4; ++nt) {
        const int nb4 = n0 + wn + nt * 16 + quad * 4;
        float4 bias4 = *(const float4*)(bias + nb4);
        float bv[4] = {bias4.x, bias4.y, bias4.z, bias4.w};
#pragma unroll
        for (int mt = 0; mt < 4; ++mt) {
            const int m = m0 + wm + mt * 16 + ln;
            u16x4 hv, lv;
#pragma unroll
            for (int reg = 0; reg < 4; ++reg) {
                float c = (acc[mt][nt][reg] + bv[reg]) * scl;
                u16 hi = f32_to_bf16(c);
                hv[reg] = hi;
                lv[reg] = f32_to_bf16(c - bf16_to_f32(hi));
            }
            size_t o = (size_t)m * DD + nb4;
            *(u16x4*)&Ch[o] = hv;
            if (wlo) *(u16x4*)&Cl[o] = lv;
        }
    }
}

// ---------------------------------------------------------------------------
// Attention: one block per (b,h, 16-row q-tile). 512 threads (8 waves).
// Q fragments loaded directly from global (no Qs LDS / no entry barrier).
// ---------------------------------------------------------------------------
#define CHK 128
__global__ __launch_bounds__(512, 4)
void attn_mfma(const u16* __restrict__ Ph, const u16* __restrict__ Pl,
               const float* __restrict__ mask, const float* __restrict__ span,
               float* __restrict__ outp, float* __restrict__ lossp)
{
    __shared__ alignas(16) u16 Kth[CHK][72];
    __shared__ alignas(16) u16 Ktl[CHK][72];
    __shared__ float curb[16][516];
    __shared__ float lred[8];

    const int t = threadIdx.x;
    const int blk = blockIdx.x;
    const int qt = blk & 31;
    const int bh = blk >> 5;
    const int b = bh / HH, h = bh % HH;
    const int w = t >> 6, l = t & 63, quad = l >> 4, ln = l & 15;
    const int r = t >> 5, j = t & 31;
    const int qrow = qt * 16 + r;

    float smbr[16];   // soft mask, registers (row-op mapping owns (r, c=u*32+j))

    auto compute_scores = [&](const u16* Qh, const u16* Ql,
                              const u16* Kh, const u16* Kl, bool use_lo) {
        // Q fragments: direct global loads (A-operand layout: row=ln, k=quad*8+j)
        const u16* qb = Qh + (size_t)(b * SS + qt * 16 + ln) * DD + h * DKK;
        short8 ah0 = *(const short8*)(qb + quad * 8);
        short8 ah1 = *(const short8*)(qb + 32 + quad * 8);
        short8 al0 = ah0, al1 = ah1;
        if (use_lo) {
            const u16* qb2 = Ql + (size_t)(b * SS + qt * 16 + ln) * DD + h * DKK;
            al0 = *(const short8*)(qb2 + quad * 8);
            al1 = *(const short8*)(qb2 + 32 + quad * 8);
        }
        for (int kc = 0; kc < SS / CHK; ++kc) {
            {
                int row = t >> 2, co = (t & 3) * 16;
                const u16* src = Kh + (size_t)(b * SS + kc * CHK + row) * DD + h * DKK + co;
                *(uint4*)&Kth[row][co]     = *(const uint4*)(src);
                *(uint4*)&Kth[row][co + 8] = *(const uint4*)(src + 8);
                if (use_lo) {
                    const u16* src2 = Kl + (size_t)(b * SS + kc * CHK + row) * DD + h * DKK + co;
                    *(uint4*)&Ktl[row][co]     = *(const uint4*)(src2);
                    *(uint4*)&Ktl[row][co + 8] = *(const uint4*)(src2 + 8);
                }
            }
            __syncthreads();
            const int nb = w * 16;
            short8 bh0 = *(const short8*)&Kth[nb + ln][quad * 8];
            short8 bh1 = *(const short8*)&Kth[nb + ln][32 + quad * 8];
            f32x4 acc = (f32x4){0.f, 0.f, 0.f, 0.f};
            acc = MFMA16(ah0, bh0, acc, 0, 0, 0);
            acc = MFMA16(ah1, bh1, acc, 0, 0, 0);
            if (use_lo) {
                short8 bl0 = *(const short8*)&Ktl[nb + ln][quad * 8];
                short8 bl1 = *(const short8*)&Ktl[nb + ln][32 + quad * 8];
                acc = MFMA16(ah0, bl0, acc, 0, 0, 0);
                acc = MFMA16(ah1, bl1, acc, 0, 0, 0);
                acc = MFMA16(al0, bh0, acc, 0, 0, 0);
                acc = MFMA16(al1, bh1, acc, 0, 0, 0);
            }
            const int cbase = kc * CHK + nb + ln;
#pragma unroll
            for (int reg = 0; reg < 4; ++reg)
                curb[quad * 4 + reg][cbase] = acc[reg];
            __syncthreads();
        }
    };

    // ---------------- Stage L ----------------
    compute_scores(Ph + 0 * (size_t)NPROJ, Pl + 0 * (size_t)NPROJ,
                   Ph + 1 * (size_t)NPROJ, Pl + 1 * (size_t)NPROJ, true);
    {
        float e[16];
        float mx = -3.0e38f;
#pragma unroll
        for (int u = 0; u < 16; ++u) {
            int c = u * 32 + j;
            float v = curb[r][c];
            if (c <= qrow && v > mx) mx = v;
        }
#pragma unroll
        for (int off = 16; off >= 1; off >>= 1) mx = fmaxf(mx, __shfl_xor(mx, off));
        float sum = 0.0f;
#pragma unroll
        for (int u = 0; u < 16; ++u) {
            int c = u * 32 + j;
            float v = (c <= qrow) ? __expf(curb[r][c] - mx) : 0.0f;
            e[u] = v; sum += v;
        }
#pragma unroll
        for (int off = 16; off >= 1; off >>= 1) sum += __shfl_xor(sum, off);
        float inv = 1.0f / sum;
        float run = 0.0f;
#pragma unroll
        for (int u = 0; u < 16; ++u) {
            float sc = e[u];
#pragma unroll
            for (int off = 1; off < 32; off <<= 1) {
                float ww = __shfl_up(sc, off, 32);
                if (j >= off) sc += ww;
            }
            smbr[u] = (run + sc) * inv;
            run += __shfl(sc, 31, 32);
        }
    }

    // ---------------- Stage R ----------------
    compute_scores(Ph + 2 * (size_t)NPROJ, Pl + 2 * (size_t)NPROJ,
                   Ph + 3 * (size_t)NPROJ, Pl + 3 * (size_t)NPROJ, true);
    {
        float e[16];
        float mx = -3.0e38f;
#pragma unroll
        for (int u = 0; u < 16; ++u) {
            int c = u * 32 + j;
            float v = curb[r][c];
            if (c >= qrow && v > mx) mx = v;
        }
#pragma unroll
        for (int off = 16; off >= 1; off >>= 1) mx = fmaxf(mx, __shfl_xor(mx, off));
        float sum = 0.0f;
#pragma unroll
        for (int u = 0; u < 16; ++u) {
            int c = u * 32 + j;
            float v = (c >= qrow) ? __expf(curb[r][c] - mx) : 0.0f;
            e[u] = v; sum += v;
        }
#pragma unroll
        for (int off = 16; off >= 1; off >>= 1) sum += __shfl_xor(sum, off);
        float inv = 1.0f / sum;
        float run = 0.0f;
#pragma unroll
        for (int u = 15; u >= 0; --u) {
            float sc = e[u];
#pragma unroll
            for (int off = 1; off < 32; off <<= 1) {
                float ww = __shfl_down(sc, off, 32);
                if (j + off < 32) sc += ww;
            }
            smbr[u] *= (run + sc) * inv;
            run += __shfl(sc, 0, 32);
        }
    }

    // ---------------- Stage M ----------------
    compute_scores(Ph + 4 * (size_t)NPROJ, (const u16*)0,
                   Ph + 5 * (size_t)NPROJ, (const u16*)0, false);
    {
        float mv  = mask[b * SS + qrow];
        float rmq = (mv == -10000.0f) ? 1.0e9f : mv;
        float vb[16];
        float mx = -3.0e38f;
#pragma unroll
        for (int u = 0; u < 16; ++u) {
            int c = u * 32 + j;
            float mk  = mask[b * SS + c];
            float rmk = (mk == -10000.0f) ? 1.0e9f : mk;
            float v = (curb[r][c] - rmq - rmk) * smbr[u];
            vb[u] = v;
            mx = fmaxf(mx, v);
        }
#pragma unroll
        for (int off = 16; off >= 1; off >>= 1) mx = fmaxf(mx, __shfl_xor(mx, off));
        float sum = 0.0f;
#pragma unroll
        for (int u = 0; u < 16; ++u) {
            float ev = __expf(vb[u] - mx);
            vb[u] = ev; sum += ev;
        }
#pragma unroll
        for (int off = 16; off >= 1; off >>= 1) sum += __shfl_xor(sum, off);
        float inv = 1.0f / sum;

        float* orow = outp + (((size_t)(b * HH + h) * SS + qrow)) * SS;
        const float* sprow = span + (((size_t)(h * BB + b) * SS + qrow)) * SS;
        float lsum = 0.0f;
#pragma unroll
        for (int u = 0; u < 16; ++u) {
            int c = u * 32 + j;
            float p = vb[u] * inv;
            orow[c] = p;
            float s = sprow[c];
            lsum += __logf(1.0f + __expf(-p)) + (1.0f - s) * p;
        }
#pragma unroll
        for (int off = 32; off >= 1; off >>= 1) lsum += __shfl_xor(lsum, off);
        if ((t & 63) == 0) lred[t >> 6] = lsum;
        __syncthreads();
        if (t == 0) {
            float tot = 0.0f;
#pragma unroll
            for (int i = 0; i < 8; ++i) tot += lred[i];
            atomicAdd(lossp, tot * (float)(1.0 / 25165824.0));
        }
    }
}

extern "C" void kernel_launch(void* const* d_in, const int* in_sizes, int n_in,
                              void* d_out, int out_size, void* d_ws, size_t ws_size,
                              hipStream_t stream)
{
    const float* query = (const float*)d_in[0];
    const float* key_t = (const float*)d_in[1];
    const float* mask  = (const float*)d_in[2];
    const float* span  = (const float*)d_in[3];
    const float* Wql = (const float*)d_in[4];  const float* bql = (const float*)d_in[5];
    const float* Wkl = (const float*)d_in[6];  const float* bkl = (const float*)d_in[7];
    const float* Wqr = (const float*)d_in[8];  const float* bqr = (const float*)d_in[9];
    const float* Wkr = (const float*)d_in[10]; const float* bkr = (const float*)d_in[11];
    const float* Wq  = (const float*)d_in[12]; const float* bq  = (const float*)d_in[13];
    const float* Wk  = (const float*)d_in[14]; const float* bk  = (const float*)d_in[15];

    float* out = (float*)d_out;
    float* lossp = out + NELEM;

    // ws layout (u16): WTh[6W] WTl[6W] Ph[6P] Pl[4P] | Xh[2P] Xl[2P] (big-ws only)
    u16* ws16 = (u16*)d_ws;
    u16* WTh = ws16;
    u16* WTl = WTh + (size_t)6 * WSZ;
    u16* Ph  = WTl + (size_t)6 * WSZ;
    u16* Pl  = Ph + (size_t)6 * NPROJ;
    u16* Xh  = Pl + (size_t)4 * NPROJ;
    u16* Xl  = Xh + (size_t)2 * NPROJ;
    const size_t need_big = ((size_t)12 * WSZ + (size_t)14 * NPROJ) * 2;  // 102.24 MB
    const bool bigws = ws_size >= need_big;

    cast_wT<<<dim3(24, 24, 6), dim3(256), 0, stream>>>(
        Wql, Wkl, Wqr, Wkr, Wq, Wk, WTh, WTl, lossp);

    if (bigws) {
        cast_X<<<dim3(1536, 2), dim3(256), 0, stream>>>(query, key_t, Xh, Xl);
        proj_gemm_gld<<<dim3(DD / 128, NTOK / 128, 6), dim3(256), 0, stream>>>(
            Xh, Xl, WTh, WTl, bql, bkl, bqr, bkr, bq, bk, Ph, Pl);
    } else {
        proj_gemm_mfma<<<dim3(DD / 128, NTOK / 128, 6), dim3(256), 0, stream>>>(
            query, key_t, WTh, WTl, bql, bkl, bqr, bkr, bq, bk, Ph, Pl);
    }

    attn_mfma<<<dim3(96 * 32), dim3(512), 0, stream>>>(
        Ph, Pl, mask, span, out, lossp);
}